// Round 11
// baseline (97.805 us; speedup 1.0000x reference)
//
#include <hip/hip_runtime.h>

typedef unsigned long long u64;
typedef unsigned int u32;

constexpr int D = 48, H = 384, W = 384;
constexpr int WPR = 6;                    // 384 bits / 64 per row (real words)
constexpr int PADW = 8;                   // padded words per row: [pad, w0..w5, pad]
constexpr int NVOX = D * H * W;           // 7,077,888
constexpr int NWVOL = D * H * WPR;        // 110,592 packed words per volume
constexpr int MPAD2 = 52;                 // padded change-mask array (u64s)
constexpr int NPZ = (H + 2) * PADW;       // padded words per z-slice = 3088
constexpr int NXY = (D + 2) * PADW;       // padded words per xy slice = 400
constexpr int NTILE = D * 36;             // 1728 bit-transpose tiles (64x64)

// Banded z phase-A
constexpr int BAND = 96;                  // core rows per band
constexpr int HALO = 24;                  // halo rows each side (>= KA)
constexpr int KA = 24;                    // fixed phase-A subpasses (even)
constexpr int BROWS = BAND + 2 * HALO;    // 144 loaded rows
constexpr int NBAND = H / BAND;           // 4

// full adder: s = a+b+c (bit-sliced), cy = carry
__device__ __forceinline__ void fa(u64 a, u64 b, u64 c, u64& s, u64& cy) {
  u64 x = a ^ b;
  s = x ^ c;
  cy = (a & b) | (c & x);
}

// One Zhang-Suen subiteration for one packed word, all neighbors in registers.
__device__ __forceinline__ u64 zs_regs(u64 w00, u64 w01, u64 w02,
                                       u64 w10, u64 w11, u64 w12,
                                       u64 w20, u64 w21, u64 w22, bool first) {
  const u64 P2 = w01;                          // N
  const u64 P3 = (w01 >> 1) | (w02 << 63);     // NE
  const u64 P4 = (w11 >> 1) | (w12 << 63);     // E
  const u64 P5 = (w21 >> 1) | (w22 << 63);     // SE
  const u64 P6 = w21;                          // S
  const u64 P7 = (w21 << 1) | (w20 >> 63);     // SW
  const u64 P8 = (w11 << 1) | (w10 >> 63);     // W
  const u64 P9 = (w01 << 1) | (w00 >> 63);     // NW

  u64 s1, c1, s2, c2, s3, c3, u0, u1, v1, v2;
  fa(P2, P3, P4, s1, c1);
  fa(P5, P6, P7, s2, c2);
  fa(P8, P9, 0ull, s3, c3);
  fa(s1, s2, s3, u0, u1);
  fa(c1, c2, c3, v1, v2);
  u64 b1 = u1 ^ v1, k2 = u1 & v1;
  u64 b2 = v2 ^ k2, b3 = v2 & k2;
  u64 condB = (b1 | b2 | b3) & ~(b3 | (b2 & b1 & u0));   // 2<=B<=6

  u64 t0 = ~P2 & P3, t1 = ~P3 & P4, t2 = ~P4 & P5, t3 = ~P5 & P6;
  u64 t4 = ~P6 & P7, t5 = ~P7 & P8, t6 = ~P8 & P9, t7 = ~P9 & P2;
  fa(t0, t1, t2, s1, c1);
  fa(t3, t4, t5, s2, c2);
  fa(t6, t7, 0ull, s3, c3);
  fa(s1, s2, s3, u0, u1);
  fa(c1, c2, c3, v1, v2);
  u64 a1 = u1 ^ v1, j2 = u1 & v1;
  u64 a2 = v2 ^ j2, a3 = v2 & j2;
  u64 condA = u0 & ~(a1 | a2 | a3);                      // A == 1

  u64 cc = first ? ((~(P2 & P4 & P6)) & (~(P4 & P6 & P8)))
                 : ((~(P2 & P4 & P8)) & (~(P2 & P6 & P8)));
  return w11 & ~(condB & condA & cc);
}

// Test 3 bits (padded word indices q..q+2) of the padded change mask U.
__device__ __forceinline__ bool dirty3(const u64* U, int q) {
  const int pb = q + 64;
  const int w = pb >> 6, sh = pb & 63;
  u64 v = U[w] >> sh;
  if (sh > 61) v |= U[w + 1] << (64 - sh);
  return (v & 7ull) != 0;
}

// One pruned subiteration pass over a padded (R+2) x 8 slice in LDS (R7-proven).
template<int R, bool FIRST>
__device__ __forceinline__ void subpass(const u64* __restrict__ src, u64* __restrict__ dst,
                                        u64* rawW, const u64* rawPrev,
                                        u64* Uw, const u64* Ur,
                                        int* chgflag, int tid, int nthr) {
  constexpr int NP = (R + 2) * PADW;
  int anych = 0;
  for (int base = 0; base < NP; base += nthr) {
    const int idx = base + tid;
    int changed = 0;
    if (idx < NP) {
      const bool dirty = dirty3(Ur, idx - PADW - 1)
                       | dirty3(Ur, idx - 1)
                       | dirty3(Ur, idx + PADW - 1);
      if (dirty) {
        const u64 old = src[idx];
        u64 nw = 0;
        if (old) {
          nw = zs_regs(src[idx - PADW - 1], src[idx - PADW], src[idx - PADW + 1],
                       src[idx - 1], old, src[idx + 1],
                       src[idx + PADW - 1], src[idx + PADW], src[idx + PADW + 1], FIRST);
          changed = (nw != old);
        }
        dst[idx] = nw;
        anych |= changed;
      }
    }
    const u64 bal = __ballot(changed != 0);
    if ((tid & 63) == 0 && idx < NP) {
      const int mw = 1 + (idx >> 6);
      rawW[mw] = bal;
      Uw[mw] = bal | rawPrev[mw];
    }
  }
  if (anych) *chgflag = 1;
}

template<int MW>
__device__ __forceinline__ void init_masks(u64* raw0, u64* raw1, u64* Um0, u64* Um1,
                                           int tid, int nthr) {
  for (int t = tid; t < 4 * MPAD2; t += nthr) {
    const int arr = t / MPAD2, j = t - arr * MPAD2;
    const u64 v = ((arr & 1) && j >= 1 && j <= MW) ? ~0ull : 0ull;
    if (arr == 0) raw0[j] = v;
    else if (arr == 1) raw1[j] = v;
    else if (arr == 2) Um0[j] = v;
    else Um1[j] = v;
  }
}

// One dense xy subpass: 256 threads over a 50x8 padded slice in LDS (R10-proven).
template<bool FIRST>
__device__ __forceinline__ void xy_pass(const u64* __restrict__ S, u64* __restrict__ Dd,
                                        int lt, int* chg) {
  int anych = 0;
  for (int idx = lt; idx < NXY; idx += 256) {
    const u64 old = S[idx];
    u64 nw = 0;
    if (old) {
      nw = zs_regs(S[idx - 9], S[idx - 8], S[idx - 7],
                   S[idx - 1], old, S[idx + 1],
                   S[idx + 7], S[idx + 8], S[idx + 9], FIRST);
      anych |= (nw != old);
    }
    Dd[idx] = nw;
  }
  if (anych) *chg = 1;
}

// K2: 384 blocks. b<192 -> z band (zi=b>>2, band=b&3), exactly KA subpasses,
//     exact 96-row core written to curZ (R8-proven).
//     b>=192 -> four xy slices, 256 threads each (R10-proven).
__global__ __launch_bounds__(1024) void thin_bands_xy(const u64* __restrict__ maskP,
                                                      u64* __restrict__ skelZY,
                                                      u64* __restrict__ skelX,
                                                      u64* __restrict__ curZ) {
  __shared__ u64 smem[4 * 2 * NXY];          // 25.6 KB (band path needs 18.7+1.7)
  __shared__ u64 masks[4 * MPAD2];
  __shared__ int s_chg[2];
  __shared__ int s_xychg[2][4];
  const int b = blockIdx.x;
  const int tid = threadIdx.x;

  if (b < D * NBAND) {
    // ---------------- z band path ----------------
    constexpr int NP = (BROWS + 2) * PADW;   // 1168
    constexpr int MW = (NP + 63) >> 6;       // 19
    const int zi = b >> 2, band = b & 3;
    const int g0 = band * BAND - HALO;       // global row of rp==1
    u64* A = smem;
    u64* B = A + NP;
    u64* raw0 = masks;
    u64* raw1 = raw0 + MPAD2;
    u64* Um0 = raw1 + MPAD2;
    u64* Um1 = Um0 + MPAD2;

    for (int idx = tid; idx < NP; idx += 1024) {
      const int rp = idx >> 3, cp = idx & 7;
      const int g = g0 + rp - 1;
      u64 v = 0;
      if (rp >= 1 && rp <= BROWS && cp >= 1 && cp <= WPR && g >= 0 && g < H)
        v = maskP[(zi * H + g) * WPR + (cp - 1)];
      A[idx] = v;
      B[idx] = 0;
    }
    init_masks<MW>(raw0, raw1, Um0, Um1, tid, 1024);
    if (tid == 0) s_chg[0] = 0;
    __syncthreads();

    for (int t = 0; t < KA; t += 2) {
      subpass<BROWS, true >(A, B, raw0, raw1, Um0, Um1, &s_chg[0], tid, 1024);
      __syncthreads();
      subpass<BROWS, false>(B, A, raw1, raw0, Um1, Um0, &s_chg[0], tid, 1024);
      __syncthreads();
    }

    for (int idx = tid; idx < NP; idx += 1024) {
      const int rp = idx >> 3, cp = idx & 7;
      if (rp < 1 || rp > BROWS || cp < 1 || cp > WPR) continue;
      const int g = g0 + rp - 1;
      if (g < band * BAND || g >= band * BAND + BAND) continue;
      curZ[(zi * H + g) * WPR + (cp - 1)] = A[idx];
    }
  } else {
    // ---------------- xy path: 4 slices/block, 256 threads each ----------
    const int g = tid >> 8;            // subgroup 0..3
    const int lt = tid & 255;          // thread within subgroup
    const int s = (b - D * NBAND) * 4 + g;   // 0..383 x-slices, 384..767 y
    u64* A = smem + g * (2 * NXY);
    u64* B = A + NXY;

    if (s < W) {
      const int lane = tid & 63;
      const int wv = (lt >> 6);        // wave within subgroup 0..3
      const int xw = s >> 6, xb = s & 63;
      for (int w = wv; w < NXY; w += 4) {
        const int rp = w >> 3, cp = w & 7;
        u64 val = 0;
        if (rp >= 1 && rp <= D && cp >= 1 && cp <= WPR) {
          const int c = (cp - 1) * 64 + lane;   // c = y
          u64 bit = (maskP[((rp - 1) * H + c) * WPR + xw] >> xb) & 1ull;
          val = __ballot(bit != 0);
        }
        if (lane == 0) { A[w] = val; B[w] = 0; }
      }
    } else {
      const int yy = s - W;
      for (int idx = lt; idx < NXY; idx += 256) {
        const int rp = idx >> 3, cp = idx & 7;
        u64 v = 0;
        if (rp >= 1 && rp <= D && cp >= 1 && cp <= WPR)
          v = maskP[((rp - 1) * H + yy) * WPR + (cp - 1)];
        A[idx] = v;
        B[idx] = 0;
      }
    }
    if (lt == 0) { s_xychg[0][g] = 0; s_xychg[1][g] = 0; }
    __syncthreads();

    int k = 0;
    bool act = true;
    while (true) {
      if (act) xy_pass<true >(A, B, lt, &s_xychg[k][g]);
      __syncthreads();
      if (lt == 0) s_xychg[k ^ 1][g] = 0;
      if (act) xy_pass<false>(B, A, lt, &s_xychg[k][g]);
      __syncthreads();
      const int c0 = s_xychg[k][0] | s_xychg[k][1] | s_xychg[k][2] | s_xychg[k][3];
      if (c0 == 0) break;
      act = (s_xychg[k][g] != 0);
      k ^= 1;
    }

    for (int idx = lt; idx < NXY; idx += 256) {
      const int rp = idx >> 3, cp = idx & 7;
      if (rp < 1 || rp > D || cp < 1 || cp > WPR) continue;
      const u64 w = A[idx];
      if (!w) continue;
      if (s < W) skelX[((rp - 1) * W + s) * WPR + (cp - 1)] = w;   // exclusive
      else       atomicOr(&skelZY[((rp - 1) * H + (s - W)) * WPR + (cp - 1)], w);
    }
  }
}

// K3: b<48 -> z-slice phase-B from curZ, pruned to convergence, atomicOr skelZY.
//     b>=48 -> skelX->skelZY ballot transpose tiles (skelX complete by stream order).
__global__ __launch_bounds__(1024) void thin_z_finish(const u64* __restrict__ curZ,
                                                      u64* __restrict__ skelZY,
                                                      const u64* __restrict__ skelX) {
  __shared__ u64 smem[2 * NPZ];
  __shared__ u64 masks[4 * MPAD2];
  __shared__ int s_chg[2];
  const int b = blockIdx.x;
  const int tid = threadIdx.x;

  if (b < D) {
    constexpr int MW = (NPZ + 63) >> 6;      // 49
    u64* A = smem;
    u64* B = A + NPZ;
    u64* raw0 = masks;
    u64* raw1 = raw0 + MPAD2;
    u64* Um0 = raw1 + MPAD2;
    u64* Um1 = Um0 + MPAD2;

    for (int idx = tid; idx < NPZ; idx += 1024) {
      const int rp = idx >> 3, cp = idx & 7;
      u64 v = 0;
      if (rp >= 1 && rp <= H && cp >= 1 && cp <= WPR)
        v = curZ[(b * H + (rp - 1)) * WPR + (cp - 1)];
      A[idx] = v;
      B[idx] = 0;
    }
    init_masks<MW>(raw0, raw1, Um0, Um1, tid, 1024);
    if (tid < 2) s_chg[tid] = 0;
    __syncthreads();

    int k = 0;
    while (true) {
      subpass<H, true >(A, B, raw0, raw1, Um0, Um1, &s_chg[k], tid, 1024);
      __syncthreads();
      if (tid == 0) s_chg[k ^ 1] = 0;
      subpass<H, false>(B, A, raw1, raw0, Um1, Um0, &s_chg[k], tid, 1024);
      __syncthreads();
      if (s_chg[k] == 0) break;
      k ^= 1;
    }

    for (int idx = tid; idx < NPZ; idx += 1024) {
      const int rp = idx >> 3, cp = idx & 7;
      if (rp < 1 || rp > H || cp < 1 || cp > WPR) continue;
      const u64 w = A[idx];
      if (!w) continue;
      atomicOr(&skelZY[(b * H + (rp - 1)) * WPR + (cp - 1)], w);
    }
  } else {
    const int gw = (b - D) * 16 + (tid >> 6);   // tile id
    if (gw < NTILE) {
      const int lane = tid & 63;
      const int z = gw / 36, rem = gw - z * 36;
      const int yw = rem / 6, xw = rem - yw * 6;
      const int x = xw * 64 + lane;
      const u64 wx = skelX[(z * W + x) * WPR + yw];     // bits indexed by y
      u64 mine = 0;
      #pragma unroll 8
      for (int j = 0; j < 64; ++j) {
        u64 wj = __ballot((wx >> j) & 1ull);
        if (lane == j) mine = wj;
      }
      const int y = yw * 64 + lane;
      if (mine) atomicOr(&skelZY[(z * H + y) * WPR + xw], mine);
    }
  }
}

// Pack mask bits (v==1.0f) along x; zero the skeleton accumulators.
__global__ void init_pack(const float* __restrict__ in, u64* __restrict__ maskP,
                          u64* __restrict__ skelZY, u64* __restrict__ skelX) {
  const int lane = threadIdx.x & 63;
  const int gwave = (blockIdx.x * blockDim.x + threadIdx.x) >> 6;
  const int nwaves = (gridDim.x * blockDim.x) >> 6;
  for (int widx = gwave; widx < NWVOL; widx += nwaves) {
    float v = in[(size_t)widx * 64 + lane];
    u64 w = __ballot(v == 1.0f);
    if (lane == 0) {
      maskP[widx] = w;
      skelZY[widx] = 0;
      skelX[widx] = 0;
    }
  }
}

// 6-connected dilation per word (computed once into LDS) + mask + coalesced
// float4 expansion. One block = 64 words = 4096 voxels.
__global__ __launch_bounds__(256) void dilate_expand(const u64* __restrict__ maskP,
                                                     const u64* __restrict__ skelZY,
                                                     float* __restrict__ out) {
  __shared__ u64 rw[64];
  const int tid = threadIdx.x;
  const int wbase = blockIdx.x * 64;
  if (tid < 64) {
    const int wi = wbase + tid;
    const int wc = wi % WPR;
    const int row = wi / WPR;        // row = z*H + y
    const int y = row % H;
    const int z = row / H;
    const u64 S = skelZY[wi];
    const u64 L = (wc > 0) ? skelZY[wi - 1] : 0ull;
    const u64 Rw = (wc < WPR - 1) ? skelZY[wi + 1] : 0ull;
    u64 d = S | (S << 1) | (L >> 63) | (S >> 1) | (Rw << 63);
    if (y > 0)     d |= skelZY[wi - WPR];
    if (y < H - 1) d |= skelZY[wi + WPR];
    if (z > 0)     d |= skelZY[wi - H * WPR];
    if (z < D - 1) d |= skelZY[wi + H * WPR];
    rw[tid] = d & maskP[wi];
  }
  __syncthreads();
  float4* o4 = reinterpret_cast<float4*>(out + (size_t)wbase * 64);
  #pragma unroll
  for (int k = 0; k < 4; ++k) {
    const int f = tid + 256 * k;
    const u64 bits = rw[f >> 4] >> ((f & 15) * 4);
    float4 o;
    o.x = (float)(bits & 1ull);
    o.y = (float)((bits >> 1) & 1ull);
    o.z = (float)((bits >> 2) & 1ull);
    o.w = (float)((bits >> 3) & 1ull);
    o4[f] = o;
  }
}

extern "C" void kernel_launch(void* const* d_in, const int* in_sizes, int n_in,
                              void* d_out, int out_size, void* d_ws, size_t ws_size,
                              hipStream_t stream) {
  const float* in = (const float*)d_in[0];
  float* out = (float*)d_out;
  u64* wsw = (u64*)d_ws;                 // need 4 * 110592 * 8 B = 3.54 MB
  u64* maskP = wsw;
  u64* skelZY = wsw + NWVOL;
  u64* skelX = wsw + 2 * NWVOL;
  u64* curZ = wsw + 3 * NWVOL;

  init_pack<<<1728, 256, 0, stream>>>(in, maskP, skelZY, skelX);
  thin_bands_xy<<<D * NBAND + 768 / 4, 1024, 0, stream>>>(maskP, skelZY, skelX, curZ);
  thin_z_finish<<<D + (NTILE + 15) / 16, 1024, 0, stream>>>(curZ, skelZY, skelX);
  dilate_expand<<<NWVOL / 64, 256, 0, stream>>>(maskP, skelZY, out);
}

// Round 12
// 65.869 us; speedup vs baseline: 1.4849x; 1.4849x over previous
//
#include <hip/hip_runtime.h>

typedef unsigned long long u64;

constexpr int D = 48, H = 384, W = 384;
constexpr int WPR = 6;                    // 384 bits / 64 per row (real words)
constexpr int PADW = 8;                   // padded words per row: [pad, w0..w5, pad]
constexpr int NVOX = D * H * W;           // 7,077,888
constexpr int NWVOL = D * H * WPR;        // 110,592 packed words per volume
constexpr int MPAD2 = 52;                 // padded change-mask array (u64s)
constexpr int NTILE = D * 36;             // 1728 bit-transpose tiles (64x64)

// full adder: s = a+b+c (bit-sliced), cy = carry
__device__ __forceinline__ void fa(u64 a, u64 b, u64 c, u64& s, u64& cy) {
  u64 x = a ^ b;
  s = x ^ c;
  cy = (a & b) | (c & x);
}

// One Zhang-Suen subiteration for one packed word, all neighbors in registers.
__device__ __forceinline__ u64 zs_regs(u64 w00, u64 w01, u64 w02,
                                       u64 w10, u64 w11, u64 w12,
                                       u64 w20, u64 w21, u64 w22, bool first) {
  const u64 P2 = w01;                          // N
  const u64 P3 = (w01 >> 1) | (w02 << 63);     // NE
  const u64 P4 = (w11 >> 1) | (w12 << 63);     // E
  const u64 P5 = (w21 >> 1) | (w22 << 63);     // SE
  const u64 P6 = w21;                          // S
  const u64 P7 = (w21 << 1) | (w20 >> 63);     // SW
  const u64 P8 = (w11 << 1) | (w10 >> 63);     // W
  const u64 P9 = (w01 << 1) | (w00 >> 63);     // NW

  u64 s1, c1, s2, c2, s3, c3, u0, u1, v1, v2;
  fa(P2, P3, P4, s1, c1);
  fa(P5, P6, P7, s2, c2);
  fa(P8, P9, 0ull, s3, c3);
  fa(s1, s2, s3, u0, u1);
  fa(c1, c2, c3, v1, v2);
  u64 b1 = u1 ^ v1, k2 = u1 & v1;
  u64 b2 = v2 ^ k2, b3 = v2 & k2;
  u64 condB = (b1 | b2 | b3) & ~(b3 | (b2 & b1 & u0));   // 2<=B<=6

  u64 t0 = ~P2 & P3, t1 = ~P3 & P4, t2 = ~P4 & P5, t3 = ~P5 & P6;
  u64 t4 = ~P6 & P7, t5 = ~P7 & P8, t6 = ~P8 & P9, t7 = ~P9 & P2;
  fa(t0, t1, t2, s1, c1);
  fa(t3, t4, t5, s2, c2);
  fa(t6, t7, 0ull, s3, c3);
  fa(s1, s2, s3, u0, u1);
  fa(c1, c2, c3, v1, v2);
  u64 a1 = u1 ^ v1, j2 = u1 & v1;
  u64 a2 = v2 ^ j2, a3 = v2 & j2;
  u64 condA = u0 & ~(a1 | a2 | a3);                      // A == 1

  u64 cc = first ? ((~(P2 & P4 & P6)) & (~(P4 & P6 & P8)))
                 : ((~(P2 & P4 & P8)) & (~(P2 & P6 & P8)));
  return w11 & ~(condB & condA & cc);
}

// Test 3 bits (padded word indices q..q+2) of the padded change mask U.
__device__ __forceinline__ bool dirty3(const u64* U, int q) {
  const int pb = q + 64;
  const int w = pb >> 6, sh = pb & 63;
  u64 v = U[w] >> sh;
  if (sh > 61) v |= U[w + 1] << (64 - sh);
  return (v & 7ull) != 0;
}

// One pruned subiteration pass over a padded (R+2) x 8 slice in LDS (R7-proven).
// Clean words (no change in 3x3 word-halo over the last two passes) are fully
// skipped: dst already holds the correct value from two passes ago.
template<int R, bool FIRST>
__device__ __forceinline__ void subpass(const u64* __restrict__ src, u64* __restrict__ dst,
                                        u64* rawW, const u64* rawPrev,
                                        u64* Uw, const u64* Ur,
                                        int* chgflag, int tid, int nthr) {
  constexpr int NP = (R + 2) * PADW;
  int anych = 0;
  for (int base = 0; base < NP; base += nthr) {
    const int idx = base + tid;
    int changed = 0;
    if (idx < NP) {
      const bool dirty = dirty3(Ur, idx - PADW - 1)
                       | dirty3(Ur, idx - 1)
                       | dirty3(Ur, idx + PADW - 1);
      if (dirty) {
        const u64 old = src[idx];
        u64 nw = 0;
        if (old) {
          nw = zs_regs(src[idx - PADW - 1], src[idx - PADW], src[idx - PADW + 1],
                       src[idx - 1], old, src[idx + 1],
                       src[idx + PADW - 1], src[idx + PADW], src[idx + PADW + 1], FIRST);
          changed = (nw != old);
        }
        dst[idx] = nw;
        anych |= changed;
      }
    }
    // threads in a wave handle 64 consecutive, 64-aligned padded words
    const u64 bal = __ballot(changed != 0);
    if ((tid & 63) == 0 && idx < NP) {
      const int mw = 1 + (idx >> 6);
      rawW[mw] = bal;
      Uw[mw] = bal | rawPrev[mw];
    }
  }
  if (anych) *chgflag = 1;
}

// Full per-slice thinning to convergence; result stored to a PRIVATE buffer
// with exclusive full word coverage (no atomics, no pre-zeroing needed).
// MODE 0: slice=z (rows=y, cols=x)  -> skelZ[(z*H+y)*WPR+xw]
// MODE 1: slice=y (rows=z, cols=x)  -> skelY[(z*H+y)*WPR+xw]
// MODE 2: slice=x (rows=z, cols=y)  -> skelX[(z*W+x)*WPR+yw]
template<int R, int MODE>
__device__ __forceinline__ void thin_body(const u64* __restrict__ maskP,
                                          u64* __restrict__ dstBuf,
                                          int slice, u64* Abuf, u64* Bbuf,
                                          u64 (*raw)[MPAD2], u64 (*Um)[MPAD2],
                                          int* s_chg) {
  constexpr int NP = (R + 2) * PADW;
  constexpr int MW = (NP + 63) >> 6;
  const int tid = threadIdx.x;
  const int nthr = blockDim.x;

  // ---- load packed slice into padded LDS (zero borders), zero Bbuf ----
  if (MODE == 0 || MODE == 1) {
    for (int idx = tid; idx < NP; idx += nthr) {
      const int rp = idx >> 3, cp = idx & 7;
      u64 v = 0;
      if (rp >= 1 && rp <= R && cp >= 1 && cp <= 6) {
        if (MODE == 0) v = maskP[(slice * H + (rp - 1)) * WPR + (cp - 1)];
        else           v = maskP[((rp - 1) * H + slice) * WPR + (cp - 1)];
      }
      Abuf[idx] = v;
      Bbuf[idx] = 0;
    }
  } else {
    const int lane = tid & 63, wave = tid >> 6, nwv = nthr >> 6;
    const int xw = slice >> 6, xb = slice & 63;
    for (int w = wave; w < NP; w += nwv) {
      const int rp = w >> 3, cp = w & 7;
      u64 val = 0;
      if (rp >= 1 && rp <= R && cp >= 1 && cp <= 6) {
        const int c = (cp - 1) * 64 + lane;               // c = y
        u64 bit = (maskP[((rp - 1) * H + c) * WPR + xw] >> xb) & 1ull;
        val = __ballot(bit != 0);
      }
      if (lane == 0) { Abuf[w] = val; Bbuf[w] = 0; }
    }
  }

  // init masks: ones on the "previous" arrays (forces first two passes dirty)
  for (int t = tid; t < 4 * MPAD2; t += nthr) {
    const int arr = t / MPAD2, j = t - arr * MPAD2;
    const u64 v = ((arr & 1) && j >= 1 && j <= MW) ? ~0ull : 0ull;
    if (arr < 2) raw[arr][j] = v; else Um[arr - 2][j] = v;
  }
  if (tid < 2) s_chg[tid] = 0;
  __syncthreads();

  // ---- iterate Zhang-Suen to convergence, word-pruned; 2 barriers/iter ----
  int k = 0;
  while (true) {
    subpass<R, true >(Abuf, Bbuf, raw[0], raw[1], Um[0], Um[1], &s_chg[k], tid, nthr);
    __syncthreads();
    if (tid == 0) s_chg[k ^ 1] = 0;   // prep next iter's slot
    subpass<R, false>(Bbuf, Abuf, raw[1], raw[0], Um[1], Um[0], &s_chg[k], tid, nthr);
    __syncthreads();
    if (s_chg[k] == 0) break;
    k ^= 1;
  }

  // ---- writeback: exclusive full coverage, plain stores ----
  for (int idx = tid; idx < NP; idx += nthr) {
    const int rp = idx >> 3, cp = idx & 7;
    if (rp < 1 || rp > R || cp < 1 || cp > 6) continue;
    const u64 w = Abuf[idx];
    const int r = rp - 1, wc = cp - 1;
    if (MODE == 0)      dstBuf[(slice * H + r) * WPR + wc] = w;
    else if (MODE == 1) dstBuf[(r * H + slice) * WPR + wc] = w;
    else                dstBuf[(r * W + slice) * WPR + wc] = w;
  }
}

__global__ __launch_bounds__(1024) void thin_all(const u64* __restrict__ maskP,
                                                 u64* __restrict__ skelZ,
                                                 u64* __restrict__ skelY,
                                                 u64* __restrict__ skelX) {
  __shared__ u64 Abuf[(H + 2) * PADW];  // sized for the largest mode (z-slices)
  __shared__ u64 Bbuf[(H + 2) * PADW];
  __shared__ u64 raw[2][MPAD2];
  __shared__ u64 Um[2][MPAD2];
  __shared__ int s_chg[2];
  const int b = blockIdx.x;
  if (b < D) {
    thin_body<H, 0>(maskP, skelZ, b, Abuf, Bbuf, raw, Um, s_chg);
  } else if (b < D + H) {
    thin_body<D, 1>(maskP, skelY, b - D, Abuf, Bbuf, raw, Um, s_chg);
  } else {
    thin_body<D, 2>(maskP, skelX, b - D - H, Abuf, Bbuf, raw, Um, s_chg);
  }
}

// Pack mask bits (v==1.0f) along x into maskP. No other init needed.
__global__ void init_pack(const float* __restrict__ in, u64* __restrict__ maskP) {
  const int lane = threadIdx.x & 63;
  const int gwave = (blockIdx.x * blockDim.x + threadIdx.x) >> 6;
  const int nwaves = (gridDim.x * blockDim.x) >> 6;
  for (int widx = gwave; widx < NWVOL; widx += nwaves) {
    float v = in[(size_t)widx * 64 + lane];
    u64 w = __ballot(v == 1.0f);
    if (lane == 0) maskP[widx] = w;
  }
}

// Bit-transpose skelX ([z][x][yw], packed y) -> skelXT ([z][y][xw], packed x).
// One wave per 64x64 bit tile; every word written (exclusive, no init needed).
__global__ void transpose_x(const u64* __restrict__ skelX,
                            u64* __restrict__ skelXT) {
  const int gw = (blockIdx.x * blockDim.x + threadIdx.x) >> 6;   // tile id
  const int lane = threadIdx.x & 63;
  const int z = gw / 36, rem = gw - z * 36;
  const int yw = rem / 6, xw = rem - yw * 6;
  const int x = xw * 64 + lane;
  const u64 wx = skelX[(z * W + x) * WPR + yw];   // bits indexed by y
  u64 mine = 0;
  #pragma unroll 8
  for (int j = 0; j < 64; ++j) {
    u64 wj = __ballot((wx >> j) & 1ull);          // bit l = pixel(y=yw*64+j, x=xw*64+l)
    if (lane == j) mine = wj;
  }
  const int y = yw * 64 + lane;
  skelXT[(z * H + y) * WPR + xw] = mine;
}

// 6-connected dilation of (skelZ | skelY | skelXT) + mask + coalesced float4
// expansion. One block = 64 words = 4096 voxels. Dilation distributes over
// union, so merging at read time is exact.
__global__ __launch_bounds__(256) void dilate_expand(const u64* __restrict__ maskP,
                                                     const u64* __restrict__ sZ,
                                                     const u64* __restrict__ sY,
                                                     const u64* __restrict__ sXT,
                                                     float* __restrict__ out) {
  __shared__ u64 rw[64];
  const int tid = threadIdx.x;
  const int wbase = blockIdx.x * 64;
  if (tid < 64) {
    const int wi = wbase + tid;
    const int wc = wi % WPR;
    const int row = wi / WPR;        // row = z*H + y
    const int y = row % H;
    const int z = row / H;
    const u64 S = sZ[wi] | sY[wi] | sXT[wi];
    const u64 L = (wc > 0) ? (sZ[wi - 1] | sY[wi - 1] | sXT[wi - 1]) : 0ull;
    const u64 Rw = (wc < WPR - 1) ? (sZ[wi + 1] | sY[wi + 1] | sXT[wi + 1]) : 0ull;
    u64 d = S | (S << 1) | (L >> 63) | (S >> 1) | (Rw << 63);
    if (y > 0)     d |= sZ[wi - WPR] | sY[wi - WPR] | sXT[wi - WPR];
    if (y < H - 1) d |= sZ[wi + WPR] | sY[wi + WPR] | sXT[wi + WPR];
    if (z > 0)     d |= sZ[wi - H * WPR] | sY[wi - H * WPR] | sXT[wi - H * WPR];
    if (z < D - 1) d |= sZ[wi + H * WPR] | sY[wi + H * WPR] | sXT[wi + H * WPR];
    rw[tid] = d & maskP[wi];
  }
  __syncthreads();
  float4* o4 = reinterpret_cast<float4*>(out + (size_t)wbase * 64);
  #pragma unroll
  for (int k = 0; k < 4; ++k) {
    const int f = tid + 256 * k;             // float4 index within the block's 1024
    const u64 bits = rw[f >> 4] >> ((f & 15) * 4);
    float4 o;
    o.x = (float)(bits & 1ull);
    o.y = (float)((bits >> 1) & 1ull);
    o.z = (float)((bits >> 2) & 1ull);
    o.w = (float)((bits >> 3) & 1ull);
    o4[f] = o;
  }
}

extern "C" void kernel_launch(void* const* d_in, const int* in_sizes, int n_in,
                              void* d_out, int out_size, void* d_ws, size_t ws_size,
                              hipStream_t stream) {
  const float* in = (const float*)d_in[0];
  float* out = (float*)d_out;
  u64* wsw = (u64*)d_ws;                 // need 5 * 110592 * 8 B = 4.42 MB
  u64* maskP = wsw;
  u64* skelZ = wsw + NWVOL;
  u64* skelY = wsw + 2 * NWVOL;
  u64* skelX = wsw + 3 * NWVOL;
  u64* skelXT = wsw + 4 * NWVOL;

  init_pack<<<1728, 256, 0, stream>>>(in, maskP);
  thin_all<<<D + H + W, 1024, 0, stream>>>(maskP, skelZ, skelY, skelX);
  transpose_x<<<(NTILE * 64) / 256, 256, 0, stream>>>(skelX, skelXT);
  dilate_expand<<<NWVOL / 64, 256, 0, stream>>>(maskP, skelZ, skelY, skelXT, out);
}

// Round 13
// 61.972 us; speedup vs baseline: 1.5782x; 1.0629x over previous
//
#include <hip/hip_runtime.h>

typedef unsigned long long u64;

constexpr int D = 48, H = 384, W = 384;
constexpr int WPR = 6;                    // 384 bits / 64 per row (real words)
constexpr int PADW = 8;                   // padded words per row: [pad, w0..w5, pad]
constexpr int NVOX = D * H * W;           // 7,077,888
constexpr int NWVOL = D * H * WPR;        // 110,592 packed words per volume
constexpr int MPAD2 = 52;                 // padded change-mask array (u64s)
constexpr int NXY = (D + 2) * PADW;       // padded words per xy slice = 400
constexpr int NTILE = D * 36;             // 1728 bit-transpose tiles (64x64)

// full adder: s = a+b+c (bit-sliced), cy = carry
__device__ __forceinline__ void fa(u64 a, u64 b, u64 c, u64& s, u64& cy) {
  u64 x = a ^ b;
  s = x ^ c;
  cy = (a & b) | (c & x);
}

// One Zhang-Suen subiteration for one packed word, all neighbors in registers.
__device__ __forceinline__ u64 zs_regs(u64 w00, u64 w01, u64 w02,
                                       u64 w10, u64 w11, u64 w12,
                                       u64 w20, u64 w21, u64 w22, bool first) {
  const u64 P2 = w01;                          // N
  const u64 P3 = (w01 >> 1) | (w02 << 63);     // NE
  const u64 P4 = (w11 >> 1) | (w12 << 63);     // E
  const u64 P5 = (w21 >> 1) | (w22 << 63);     // SE
  const u64 P6 = w21;                          // S
  const u64 P7 = (w21 << 1) | (w20 >> 63);     // SW
  const u64 P8 = (w11 << 1) | (w10 >> 63);     // W
  const u64 P9 = (w01 << 1) | (w00 >> 63);     // NW

  u64 s1, c1, s2, c2, s3, c3, u0, u1, v1, v2;
  fa(P2, P3, P4, s1, c1);
  fa(P5, P6, P7, s2, c2);
  fa(P8, P9, 0ull, s3, c3);
  fa(s1, s2, s3, u0, u1);
  fa(c1, c2, c3, v1, v2);
  u64 b1 = u1 ^ v1, k2 = u1 & v1;
  u64 b2 = v2 ^ k2, b3 = v2 & k2;
  u64 condB = (b1 | b2 | b3) & ~(b3 | (b2 & b1 & u0));   // 2<=B<=6

  u64 t0 = ~P2 & P3, t1 = ~P3 & P4, t2 = ~P4 & P5, t3 = ~P5 & P6;
  u64 t4 = ~P6 & P7, t5 = ~P7 & P8, t6 = ~P8 & P9, t7 = ~P9 & P2;
  fa(t0, t1, t2, s1, c1);
  fa(t3, t4, t5, s2, c2);
  fa(t6, t7, 0ull, s3, c3);
  fa(s1, s2, s3, u0, u1);
  fa(c1, c2, c3, v1, v2);
  u64 a1 = u1 ^ v1, j2 = u1 & v1;
  u64 a2 = v2 ^ j2, a3 = v2 & j2;
  u64 condA = u0 & ~(a1 | a2 | a3);                      // A == 1

  u64 cc = first ? ((~(P2 & P4 & P6)) & (~(P4 & P6 & P8)))
                 : ((~(P2 & P4 & P8)) & (~(P2 & P6 & P8)));
  return w11 & ~(condB & condA & cc);
}

// Wave-frame dirty test (z path). Lane l (word idx = wb + l, wb 64-aligned)
// needs: dirty3(U, idx-9) | dirty3(U, idx-1) | dirty3(U, idx+7), where
// dirty3(U,q) tests logical bits q..q+2 of the padded mask (logical word i at
// array bit 64+i). Define smeared logical bits sm[i] = U[i]|U[i+1]|U[i+2];
// then dirty = sm[idx-9] | sm[idx-1] | sm[idx+7]. With A,B,C,Dw = array words
// mw-1..mw+2 (mw = 1 + wb/64; U[mw] covers logical [wb, wb+64)):
//   smA = A | (A>>1 | B<<63) | (A>>2 | B<<62)   covers logical [wb-64, wb)
//   smB = B | (B>>1 | C<<63) | (B>>2 | C<<62)   covers [wb, wb+64)
//   smC = C | (C>>1 | Dw<<63)| (C>>2 | Dw<<62)  covers [wb+64, wb+128)
//   Dm9 = (smB<<9) | (smA>>55);  Dm1 = (smB<<1) | (smA>>63);
//   Dp7 = (smB>>7) | (smC<<57);
//   dirty_l = ((Dm9 | Dm1 | Dp7) >> l) & 1
// Verified: bit l of Dm9 = sm[wb+l-9] (l>=9 from smB, l<9 from smA tail), etc.
__device__ __forceinline__ u64 dirty_wave(const u64* __restrict__ U, int mw) {
  const u64 A = U[mw - 1], B = U[mw], C = U[mw + 1], Dw = U[mw + 2];
  const u64 smA = A | (A >> 1 | B << 63) | (A >> 2 | B << 62);
  const u64 smB = B | (B >> 1 | C << 63) | (B >> 2 | C << 62);
  const u64 smC = C | (C >> 1 | Dw << 63) | (C >> 2 | Dw << 62);
  const u64 Dm9 = (smB << 9) | (smA >> 55);
  const u64 Dm1 = (smB << 1) | (smA >> 63);
  const u64 Dp7 = (smB >> 7) | (smC << 57);
  return Dm9 | Dm1 | Dp7;
}

// One pruned subiteration pass over the padded (R+2) x 8 z-slice in LDS.
// Clean words (no change in 3x3 word-halo over the last two passes) are fully
// skipped: dst already holds the correct value from two passes ago.
template<int R, bool FIRST>
__device__ __forceinline__ void subpass(const u64* __restrict__ src, u64* __restrict__ dst,
                                        u64* rawW, const u64* rawPrev,
                                        u64* Uw, const u64* Ur,
                                        int* chgflag, int tid, int nthr) {
  constexpr int NP = (R + 2) * PADW;
  int anych = 0;
  for (int base = 0; base < NP; base += nthr) {
    const int idx = base + tid;
    int changed = 0;
    if (idx < NP) {
      const int mw = 1 + (idx >> 6);
      const u64 dmask = dirty_wave(Ur, mw);      // same for all lanes of the wave
      if ((dmask >> (idx & 63)) & 1ull) {
        const u64 old = src[idx];
        u64 nw = 0;
        if (old) {
          nw = zs_regs(src[idx - PADW - 1], src[idx - PADW], src[idx - PADW + 1],
                       src[idx - 1], old, src[idx + 1],
                       src[idx + PADW - 1], src[idx + PADW], src[idx + PADW + 1], FIRST);
          changed = (nw != old);
        }
        dst[idx] = nw;
        anych |= changed;
      }
    }
    // threads in a wave handle 64 consecutive, 64-aligned padded words
    const u64 bal = __ballot(changed != 0);
    if ((tid & 63) == 0 && idx < NP) {
      const int mw = 1 + (idx >> 6);
      rawW[mw] = bal;
      Uw[mw] = bal | rawPrev[mw];
    }
  }
  if (anych) *chgflag = 1;
}

// Dense xy subpass: no masks (barrier-dominated small slices; pruning is pure
// overhead there). Both buffers fully rewritten each pass.
template<bool FIRST>
__device__ __forceinline__ void xy_dense(const u64* __restrict__ src, u64* __restrict__ dst,
                                         int* chgflag, int tid) {
  int anych = 0;
  if (tid < NXY) {
    const u64 old = src[tid];
    u64 nw = 0;
    if (old) {
      nw = zs_regs(src[tid - PADW - 1], src[tid - PADW], src[tid - PADW + 1],
                   src[tid - 1], old, src[tid + 1],
                   src[tid + PADW - 1], src[tid + PADW], src[tid + PADW + 1], FIRST);
      anych = (nw != old);
    }
    dst[tid] = nw;
  }
  if (anych) *chgflag = 1;
}

// z-slice thinning to convergence (word-pruned), result -> private skelZ.
template<int R>
__device__ __forceinline__ void thin_z(const u64* __restrict__ maskP,
                                       u64* __restrict__ skelZ,
                                       int slice, u64* Abuf, u64* Bbuf,
                                       u64 (*raw)[MPAD2], u64 (*Um)[MPAD2],
                                       int* s_chg) {
  constexpr int NP = (R + 2) * PADW;
  constexpr int MW = (NP + 63) >> 6;
  const int tid = threadIdx.x;
  const int nthr = 1024;

  for (int idx = tid; idx < NP; idx += nthr) {
    const int rp = idx >> 3, cp = idx & 7;
    u64 v = 0;
    if (rp >= 1 && rp <= R && cp >= 1 && cp <= 6)
      v = maskP[(slice * H + (rp - 1)) * WPR + (cp - 1)];
    Abuf[idx] = v;
    Bbuf[idx] = 0;
  }
  for (int t = tid; t < 4 * MPAD2; t += nthr) {
    const int arr = t / MPAD2, j = t - arr * MPAD2;
    const u64 v = ((arr & 1) && j >= 1 && j <= MW) ? ~0ull : 0ull;
    if (arr < 2) raw[arr][j] = v; else Um[arr - 2][j] = v;
  }
  if (tid < 2) s_chg[tid] = 0;
  __syncthreads();

  int k = 0;
  while (true) {
    subpass<R, true >(Abuf, Bbuf, raw[0], raw[1], Um[0], Um[1], &s_chg[k], tid, nthr);
    __syncthreads();
    if (tid == 0) s_chg[k ^ 1] = 0;
    subpass<R, false>(Bbuf, Abuf, raw[1], raw[0], Um[1], Um[0], &s_chg[k], tid, nthr);
    __syncthreads();
    if (s_chg[k] == 0) break;
    k ^= 1;
  }

  for (int idx = tid; idx < NP; idx += nthr) {
    const int rp = idx >> 3, cp = idx & 7;
    if (rp < 1 || rp > R || cp < 1 || cp > 6) continue;
    skelZ[(slice * H + (rp - 1)) * WPR + (cp - 1)] = Abuf[idx];
  }
}

// xy-slice thinning to convergence (dense), result -> private buffer.
// MODE 1: slice=y (rows=z, cols=x) -> skelY[(z*H+y)*WPR+xw]
// MODE 2: slice=x (rows=z, cols=y) -> skelX[(z*W+x)*WPR+yw]
template<int MODE>
__device__ __forceinline__ void thin_xy(const u64* __restrict__ maskP,
                                        u64* __restrict__ dstBuf,
                                        int slice, u64* Abuf, u64* Bbuf,
                                        int* s_chg) {
  const int tid = threadIdx.x;

  if (MODE == 1) {
    if (tid < NXY) {
      const int rp = tid >> 3, cp = tid & 7;
      u64 v = 0;
      if (rp >= 1 && rp <= D && cp >= 1 && cp <= 6)
        v = maskP[((rp - 1) * H + slice) * WPR + (cp - 1)];
      Abuf[tid] = v;
      Bbuf[tid] = 0;
    }
  } else {
    const int lane = tid & 63, wave = tid >> 6;
    const int xw = slice >> 6, xb = slice & 63;
    for (int w = wave; w < NXY; w += 16) {
      const int rp = w >> 3, cp = w & 7;
      u64 val = 0;
      if (rp >= 1 && rp <= D && cp >= 1 && cp <= 6) {
        const int c = (cp - 1) * 64 + lane;               // c = y
        u64 bit = (maskP[((rp - 1) * H + c) * WPR + xw] >> xb) & 1ull;
        val = __ballot(bit != 0);
      }
      if (lane == 0) { Abuf[w] = val; Bbuf[w] = 0; }
    }
  }
  if (tid < 2) s_chg[tid] = 0;
  __syncthreads();

  int k = 0;
  while (true) {
    xy_dense<true >(Abuf, Bbuf, &s_chg[k], tid);
    __syncthreads();
    if (tid == 0) s_chg[k ^ 1] = 0;
    xy_dense<false>(Bbuf, Abuf, &s_chg[k], tid);
    __syncthreads();
    if (s_chg[k] == 0) break;
    k ^= 1;
  }

  if (tid < NXY) {
    const int rp = tid >> 3, cp = tid & 7;
    if (rp >= 1 && rp <= D && cp >= 1 && cp <= 6) {
      const u64 w = Abuf[tid];
      if (MODE == 1) dstBuf[((rp - 1) * H + slice) * WPR + (cp - 1)] = w;
      else           dstBuf[((rp - 1) * W + slice) * WPR + (cp - 1)] = w;
    }
  }
}

__global__ __launch_bounds__(1024) void thin_all(const u64* __restrict__ maskP,
                                                 u64* __restrict__ skelZ,
                                                 u64* __restrict__ skelY,
                                                 u64* __restrict__ skelX) {
  __shared__ u64 Abuf[(H + 2) * PADW];  // sized for the largest mode (z-slices)
  __shared__ u64 Bbuf[(H + 2) * PADW];
  __shared__ u64 raw[2][MPAD2];
  __shared__ u64 Um[2][MPAD2];
  __shared__ int s_chg[2];
  const int b = blockIdx.x;
  if (b < D) {
    thin_z<H>(maskP, skelZ, b, Abuf, Bbuf, raw, Um, s_chg);
  } else if (b < D + H) {
    thin_xy<1>(maskP, skelY, b - D, Abuf, Bbuf, s_chg);
  } else {
    thin_xy<2>(maskP, skelX, b - D - H, Abuf, Bbuf, s_chg);
  }
}

// Pack mask bits (v==1.0f) along x into maskP. No other init needed.
__global__ void init_pack(const float* __restrict__ in, u64* __restrict__ maskP) {
  const int lane = threadIdx.x & 63;
  const int gwave = (blockIdx.x * blockDim.x + threadIdx.x) >> 6;
  const int nwaves = (gridDim.x * blockDim.x) >> 6;
  for (int widx = gwave; widx < NWVOL; widx += nwaves) {
    float v = in[(size_t)widx * 64 + lane];
    u64 w = __ballot(v == 1.0f);
    if (lane == 0) maskP[widx] = w;
  }
}

// Bit-transpose skelX ([z][x][yw], packed y) -> skelXT ([z][y][xw], packed x).
// One wave per 64x64 bit tile; every word written (exclusive, no init needed).
__global__ void transpose_x(const u64* __restrict__ skelX,
                            u64* __restrict__ skelXT) {
  const int gw = (blockIdx.x * blockDim.x + threadIdx.x) >> 6;   // tile id
  const int lane = threadIdx.x & 63;
  const int z = gw / 36, rem = gw - z * 36;
  const int yw = rem / 6, xw = rem - yw * 6;
  const int x = xw * 64 + lane;
  const u64 wx = skelX[(z * W + x) * WPR + yw];   // bits indexed by y
  u64 mine = 0;
  #pragma unroll 8
  for (int j = 0; j < 64; ++j) {
    u64 wj = __ballot((wx >> j) & 1ull);          // bit l = pixel(y=yw*64+j, x=xw*64+l)
    if (lane == j) mine = wj;
  }
  const int y = yw * 64 + lane;
  skelXT[(z * H + y) * WPR + xw] = mine;
}

// 6-connected dilation of (skelZ | skelY | skelXT) + mask + coalesced float4
// expansion. One block = 64 words = 4096 voxels.
__global__ __launch_bounds__(256) void dilate_expand(const u64* __restrict__ maskP,
                                                     const u64* __restrict__ sZ,
                                                     const u64* __restrict__ sY,
                                                     const u64* __restrict__ sXT,
                                                     float* __restrict__ out) {
  __shared__ u64 rw[64];
  const int tid = threadIdx.x;
  const int wbase = blockIdx.x * 64;
  if (tid < 64) {
    const int wi = wbase + tid;
    const int wc = wi % WPR;
    const int row = wi / WPR;        // row = z*H + y
    const int y = row % H;
    const int z = row / H;
    const u64 S = sZ[wi] | sY[wi] | sXT[wi];
    const u64 L = (wc > 0) ? (sZ[wi - 1] | sY[wi - 1] | sXT[wi - 1]) : 0ull;
    const u64 Rw = (wc < WPR - 1) ? (sZ[wi + 1] | sY[wi + 1] | sXT[wi + 1]) : 0ull;
    u64 d = S | (S << 1) | (L >> 63) | (S >> 1) | (Rw << 63);
    if (y > 0)     d |= sZ[wi - WPR] | sY[wi - WPR] | sXT[wi - WPR];
    if (y < H - 1) d |= sZ[wi + WPR] | sY[wi + WPR] | sXT[wi + WPR];
    if (z > 0)     d |= sZ[wi - H * WPR] | sY[wi - H * WPR] | sXT[wi - H * WPR];
    if (z < D - 1) d |= sZ[wi + H * WPR] | sY[wi + H * WPR] | sXT[wi + H * WPR];
    rw[tid] = d & maskP[wi];
  }
  __syncthreads();
  float4* o4 = reinterpret_cast<float4*>(out + (size_t)wbase * 64);
  #pragma unroll
  for (int k = 0; k < 4; ++k) {
    const int f = tid + 256 * k;             // float4 index within the block's 1024
    const u64 bits = rw[f >> 4] >> ((f & 15) * 4);
    float4 o;
    o.x = (float)(bits & 1ull);
    o.y = (float)((bits >> 1) & 1ull);
    o.z = (float)((bits >> 2) & 1ull);
    o.w = (float)((bits >> 3) & 1ull);
    o4[f] = o;
  }
}

extern "C" void kernel_launch(void* const* d_in, const int* in_sizes, int n_in,
                              void* d_out, int out_size, void* d_ws, size_t ws_size,
                              hipStream_t stream) {
  const float* in = (const float*)d_in[0];
  float* out = (float*)d_out;
  u64* wsw = (u64*)d_ws;                 // need 5 * 110592 * 8 B = 4.42 MB
  u64* maskP = wsw;
  u64* skelZ = wsw + NWVOL;
  u64* skelY = wsw + 2 * NWVOL;
  u64* skelX = wsw + 3 * NWVOL;
  u64* skelXT = wsw + 4 * NWVOL;

  init_pack<<<1728, 256, 0, stream>>>(in, maskP);
  thin_all<<<D + H + W, 1024, 0, stream>>>(maskP, skelZ, skelY, skelX);
  transpose_x<<<(NTILE * 64) / 256, 256, 0, stream>>>(skelX, skelXT);
  dilate_expand<<<NWVOL / 64, 256, 0, stream>>>(maskP, skelZ, skelY, skelXT, out);
}